// Round 5
// baseline (670.763 us; speedup 1.0000x reference)
//
#include <hip/hip_runtime.h>
#include <hip/hip_bf16.h>
#include <cmath>

#define NT 4096      // B*S tokens
#define HD 768
#define ID 3072
#define NE 7
#define NP 8192      // NT * TOP_K
#define TM 128
#define TN 256
#define BK 32        // 4 chunks of 8 bf16 per row per iter (per buffer)
#define KS 4         // split-K factor for ffn2

using short8 = __attribute__((ext_vector_type(8))) short;
using f32x4  = __attribute__((ext_vector_type(4))) float;
typedef __hip_bfloat16 bf16;

// async global->LDS, 16B per lane, wave-uniform base + lane*16
typedef const __attribute__((address_space(1))) void* gas_ptr;
typedef __attribute__((address_space(3))) void* las_ptr;
#define GLDS(g, l) __builtin_amdgcn_global_load_lds((gas_ptr)(g), (las_ptr)(l), 16, 0, 0)

__device__ inline float b2f(unsigned short u) {
  unsigned v = (unsigned)u << 16; float f; __builtin_memcpy(&f, &v, 4); return f;
}

// ---------------- gating: logits, top-2 softmax, routing lists, x->bf16 ----------------
__global__ __launch_bounds__(64) void gate_kernel(
    const float* __restrict__ x, const float* __restrict__ wg, const float* __restrict__ bg,
    float* __restrict__ gate_out, bf16* __restrict__ xb,
    float* __restrict__ pair_w, int* __restrict__ elist, int* __restrict__ counts)
{
  int t = blockIdx.x;
  int lane = threadIdx.x;
  const float* xr = x + (size_t)t * HD;
  float acc[NE];
#pragma unroll
  for (int e = 0; e < NE; e++) acc[e] = 0.f;
#pragma unroll
  for (int j = 0; j < HD / 64; j++) {
    int h = lane + j * 64;
    float xv = xr[h];
    xb[(size_t)t * HD + h] = __float2bfloat16(xv);
    const float* wr = wg + (size_t)h * NE;
#pragma unroll
    for (int e = 0; e < NE; e++) acc[e] += xv * wr[e];
  }
#pragma unroll
  for (int e = 0; e < NE; e++) {
    float v = acc[e];
    for (int s = 32; s > 0; s >>= 1) v += __shfl_down(v, s, 64);
    acc[e] = v;
  }
  if (lane == 0) {
    float lg[NE];
#pragma unroll
    for (int e = 0; e < NE; e++) lg[e] = acc[e] + bg[e];
    int i0 = 0;
    for (int e = 1; e < NE; e++) if (lg[e] > lg[i0]) i0 = e;  // first index wins ties
    int i1 = -1;
    for (int e = 0; e < NE; e++) {
      if (e == i0) continue;
      if (i1 < 0 || lg[e] > lg[i1]) i1 = e;
    }
    float v0 = lg[i0], v1 = lg[i1];
    float e1 = expf(v1 - v0);
    float inv = 1.f / (1.f + e1);
    float w0 = inv, w1v = e1 * inv;
    float* go = gate_out + (size_t)t * NE;
#pragma unroll
    for (int e = 0; e < NE; e++) go[e] = 0.f;
    go[i0] = w0; go[i1] = w1v;
    pair_w[2 * t + 0] = w0;
    pair_w[2 * t + 1] = w1v;
    int p0 = atomicAdd(&counts[i0], 1);
    elist[i0 * NP + p0] = 2 * t;
    int p1 = atomicAdd(&counts[i1], 1);
    elist[i1 * NP + p1] = 2 * t + 1;
  }
}

// ---------------- fp32 [E][K][N] -> bf16 [E][N][K] transpose ----------------
__global__ __launch_bounds__(256) void transpose_cvt_kernel(
    const float* __restrict__ src, bf16* __restrict__ dst, int K, int N)
{
  __shared__ float tile[32][33];
  int e = blockIdx.z;
  int n0 = blockIdx.x * 32;
  int k0 = blockIdx.y * 32;
  const float* s = src + (size_t)e * K * N;
  bf16* d = dst + (size_t)e * K * N;
  int tx = threadIdx.x & 31;
  int ty = threadIdx.x >> 5;  // 0..7
#pragma unroll
  for (int i = 0; i < 4; i++)
    tile[ty + i * 8][tx] = s[(size_t)(k0 + ty + i * 8) * N + n0 + tx];
  __syncthreads();
#pragma unroll
  for (int i = 0; i < 4; i++)
    d[(size_t)(n0 + ty + i * 8) * K + k0 + tx] = __float2bfloat16(tile[tx][ty + i * 8]);
}

// ================= shared GEMM machinery =================
// LDS tile (per buffer): [row][physchunk 0..3][8 bf16]; phys slot p holds logical chunk
// kc = p ^ ((row>>1)&3).  Fragment read: phys p = quad ^ ((lr>>1)&3) -> bank-group
// = 4*(lr&1) + p covers all 8 groups, 2 lanes each = conflict-free (m136).
// Staging: chunk c; row=c>>2, p=c&3 -> lane-contiguous LDS dest (GLDS-legal),
// 4 consecutive lanes cover one row's 64B (permuted within the segment).
// Double-buffered; 32 MFMAs per barrier (TN=256) to raise MFMA duty vs the vmcnt drain.

// ---------------- grouped GEMM 1: h = gelu(x_g @ W1e + b1e), bf16 out ----------------
__global__ __launch_bounds__(256) void ffn1_kernel(
    const bf16* __restrict__ xb, const bf16* __restrict__ w1t, const float* __restrict__ b1,
    const int* __restrict__ counts, const int* __restrict__ elist, bf16* __restrict__ hbuf)
{
  __shared__ bf16 As[2][TM][4][8];   // 2 x 8 KB
  __shared__ bf16 Bs[2][TN][4][8];   // 2 x 16 KB
  __shared__ int plist[TM];

  int tid = threadIdx.x;
  // grid: x = n-tile (fast, shares A across consecutive blocks), y = m-tile-linear
  int e, base = 0, cnt = 0, acct = 0;
  bool found = false;
  for (e = 0; e < NE; e++) {
    cnt = counts[e];
    int tiles = (cnt + TM - 1) / TM;
    if ((int)blockIdx.y < acct + tiles) { base = ((int)blockIdx.y - acct) * TM; found = true; break; }
    acct += tiles;
  }
  if (!found) return;

  if (tid < TM) {
    int r = base + tid;
    plist[tid] = (r < cnt) ? elist[e * NP + r] : -1;
  }
  __syncthreads();

  const int n0 = blockIdx.x * TN;
  const bf16* Bsrc = w1t + (size_t)e * ID * HD;  // [ID][HD] bf16, K-contiguous

  // A: 512 chunks (2/thread), B: 1024 chunks (4/thread)
  const bf16* ag[2]; const bf16* bgp[4];
  bf16* asd[2][2]; bf16* bsd[2][4];
#pragma unroll
  for (int i = 0; i < 2; i++) {
    int c = tid + 256 * i;
    int row = c >> 2, p = c & 3;
    int kc = p ^ ((row >> 1) & 3);
    int pr = plist[row];
    ag[i] = xb + (size_t)((pr >= 0 ? pr : 0) >> 1) * HD + kc * 8;
#pragma unroll
    for (int d = 0; d < 2; d++)
      asd[d][i] = (bf16*)As + (size_t)d * TM * 32 + (size_t)c * 8;
  }
#pragma unroll
  for (int i = 0; i < 4; i++) {
    int c = tid + 256 * i;
    int row = c >> 2, p = c & 3;
    int kc = p ^ ((row >> 1) & 3);
    bgp[i] = Bsrc + (size_t)(n0 + row) * HD + kc * 8;
#pragma unroll
    for (int d = 0; d < 2; d++)
      bsd[d][i] = (bf16*)Bs + (size_t)d * TN * 32 + (size_t)c * 8;
  }

  int wave = tid >> 6, lane = tid & 63;
  int wm = (wave & 1) << 6, wn = (wave >> 1) << 7;
  int lr = lane & 15, quad = lane >> 4;
  int ph = quad ^ ((lr >> 1) & 3);

  f32x4 acc[4][8] = {};

  const int NIT = HD / BK;  // 24
#pragma unroll
  for (int i = 0; i < 2; i++) GLDS(ag[i], asd[0][i]);
#pragma unroll
  for (int i = 0; i < 4; i++) GLDS(bgp[i], bsd[0][i]);
  __syncthreads();

  for (int it = 0; it < NIT; ++it) {
    int cur = it & 1;
    if (it + 1 < NIT) {
      int koff = (it + 1) * BK;
#pragma unroll
      for (int i = 0; i < 2; i++) GLDS(ag[i] + koff, asd[cur ^ 1][i]);
#pragma unroll
      for (int i = 0; i < 4; i++) GLDS(bgp[i] + koff, bsd[cur ^ 1][i]);
    }
    short8 af[4], bfr[8];
#pragma unroll
    for (int i = 0; i < 4; i++) af[i] = *(const short8*)&As[cur][wm + i * 16 + lr][ph][0];
#pragma unroll
    for (int j = 0; j < 8; j++) bfr[j] = *(const short8*)&Bs[cur][wn + j * 16 + lr][ph][0];
#pragma unroll
    for (int i = 0; i < 4; i++)
#pragma unroll
      for (int j = 0; j < 8; j++)
        acc[i][j] = __builtin_amdgcn_mfma_f32_16x16x32_bf16(af[i], bfr[j], acc[i][j], 0, 0, 0);
    __syncthreads();
  }

  const float* b1e = b1 + (size_t)e * ID;
#pragma unroll
  for (int j = 0; j < 8; j++) {
    int col = n0 + wn + j * 16 + lr;
    float bias = b1e[col];
#pragma unroll
    for (int i = 0; i < 4; i++) {
#pragma unroll
      for (int r = 0; r < 4; r++) {
        int mrow = wm + i * 16 + quad * 4 + r;
        int p = plist[mrow];
        if (p >= 0) {
          float v = acc[i][j][r] + bias;
          float g = 0.5f * v * (1.0f + erff(v * 0.70710678118654752f));  // exact-erf gelu
          hbuf[(size_t)p * ID + col] = __float2bfloat16(g);
        }
      }
    }
  }
}

// ---------------- grouped GEMM 2 (split-K): pout[seg] = (h @ W2e[kseg] [+b2e]) * gate_w ----------------
__global__ __launch_bounds__(256) void ffn2_kernel(
    const bf16* __restrict__ hbuf, const bf16* __restrict__ w2t, const float* __restrict__ b2,
    const int* __restrict__ counts, const int* __restrict__ elist,
    const float* __restrict__ pair_w, bf16* __restrict__ pout)
{
  __shared__ bf16 As[2][TM][4][8];
  __shared__ bf16 Bs[2][TN][4][8];
  __shared__ int plist[TM];

  int tid = threadIdx.x;
  // grid: x = n-tile (fast), y = m-tile-linear, z = k-segment
  int e, base = 0, cnt = 0, acct = 0;
  bool found = false;
  for (e = 0; e < NE; e++) {
    cnt = counts[e];
    int tiles = (cnt + TM - 1) / TM;
    if ((int)blockIdx.y < acct + tiles) { base = ((int)blockIdx.y - acct) * TM; found = true; break; }
    acct += tiles;
  }
  if (!found) return;

  if (tid < TM) {
    int r = base + tid;
    plist[tid] = (r < cnt) ? elist[e * NP + r] : -1;
  }
  __syncthreads();

  const int n0 = blockIdx.x * TN;
  const int seg = blockIdx.z;
  const int kbase = seg * (ID / KS);
  const bf16* Bsrc = w2t + (size_t)e * HD * ID;  // [HD][ID] bf16, K-contiguous

  const bf16* ag[2]; const bf16* bgp[4];
  bf16* asd[2][2]; bf16* bsd[2][4];
#pragma unroll
  for (int i = 0; i < 2; i++) {
    int c = tid + 256 * i;
    int row = c >> 2, p = c & 3;
    int kc = p ^ ((row >> 1) & 3);
    int pr = plist[row];
    ag[i] = hbuf + (size_t)(pr >= 0 ? pr : 0) * ID + kbase + kc * 8;
#pragma unroll
    for (int d = 0; d < 2; d++)
      asd[d][i] = (bf16*)As + (size_t)d * TM * 32 + (size_t)c * 8;
  }
#pragma unroll
  for (int i = 0; i < 4; i++) {
    int c = tid + 256 * i;
    int row = c >> 2, p = c & 3;
    int kc = p ^ ((row >> 1) & 3);
    bgp[i] = Bsrc + (size_t)(n0 + row) * ID + kbase + kc * 8;
#pragma unroll
    for (int d = 0; d < 2; d++)
      bsd[d][i] = (bf16*)Bs + (size_t)d * TN * 32 + (size_t)c * 8;
  }

  int wave = tid >> 6, lane = tid & 63;
  int wm = (wave & 1) << 6, wn = (wave >> 1) << 7;
  int lr = lane & 15, quad = lane >> 4;
  int ph = quad ^ ((lr >> 1) & 3);

  f32x4 acc[4][8] = {};

  const int NIT = (ID / KS) / BK;  // 24
#pragma unroll
  for (int i = 0; i < 2; i++) GLDS(ag[i], asd[0][i]);
#pragma unroll
  for (int i = 0; i < 4; i++) GLDS(bgp[i], bsd[0][i]);
  __syncthreads();

  for (int it = 0; it < NIT; ++it) {
    int cur = it & 1;
    if (it + 1 < NIT) {
      int koff = (it + 1) * BK;
#pragma unroll
      for (int i = 0; i < 2; i++) GLDS(ag[i] + koff, asd[cur ^ 1][i]);
#pragma unroll
      for (int i = 0; i < 4; i++) GLDS(bgp[i] + koff, bsd[cur ^ 1][i]);
    }
    short8 af[4], bfr[8];
#pragma unroll
    for (int i = 0; i < 4; i++) af[i] = *(const short8*)&As[cur][wm + i * 16 + lr][ph][0];
#pragma unroll
    for (int j = 0; j < 8; j++) bfr[j] = *(const short8*)&Bs[cur][wn + j * 16 + lr][ph][0];
#pragma unroll
    for (int i = 0; i < 4; i++)
#pragma unroll
      for (int j = 0; j < 8; j++)
        acc[i][j] = __builtin_amdgcn_mfma_f32_16x16x32_bf16(af[i], bfr[j], acc[i][j], 0, 0, 0);
    __syncthreads();
  }

  const float* b2e = b2 + (size_t)e * HD;
#pragma unroll
  for (int j = 0; j < 8; j++) {
    int col = n0 + wn + j * 16 + lr;
    float bias = (seg == 0) ? b2e[col] : 0.f;
#pragma unroll
    for (int i = 0; i < 4; i++) {
#pragma unroll
      for (int r = 0; r < 4; r++) {
        int mrow = wm + i * 16 + quad * 4 + r;
        int p = plist[mrow];
        if (p >= 0) {
          float v = (acc[i][j][r] + bias) * pair_w[p];
          pout[((size_t)seg * NP + p) * HD + col] = __float2bfloat16(v);
        }
      }
    }
  }
}

// ---------------- combine: out[t] = sum over 2 experts x KS k-segments ----------------
__global__ __launch_bounds__(192) void combine_kernel(
    const bf16* __restrict__ pout, float* __restrict__ out)
{
  int t = blockIdx.x, j = threadIdx.x;  // 192 threads = 768/4
  f32x4 o = {0.f, 0.f, 0.f, 0.f};
#pragma unroll
  for (int s = 0; s < KS; s++) {
#pragma unroll
    for (int k = 0; k < 2; k++) {
      const ushort4* v = (const ushort4*)(pout + ((size_t)s * NP + 2 * t + k) * HD);
      ushort4 u = v[j];
      o[0] += b2f(u.x); o[1] += b2f(u.y); o[2] += b2f(u.z); o[3] += b2f(u.w);
    }
  }
  ((f32x4*)(out + (size_t)t * HD))[j] = o;
}

extern "C" void kernel_launch(void* const* d_in, const int* in_sizes, int n_in,
                              void* d_out, int out_size, void* d_ws, size_t ws_size,
                              hipStream_t stream)
{
  const float* x  = (const float*)d_in[0];
  const float* wg = (const float*)d_in[1];
  const float* bg = (const float*)d_in[2];
  const float* w1 = (const float*)d_in[3];
  const float* b1 = (const float*)d_in[4];
  const float* w2 = (const float*)d_in[5];
  const float* b2 = (const float*)d_in[6];
  float* out = (float*)d_out;
  float* gate_out = out + (size_t)NT * HD;  // second output [B,S,E]

  // workspace layout (~166 MB total, all 16B-aligned offsets)
  char* ws = (char*)d_ws;
  size_t off = 0;
  int* counts  = (int*)(ws + off);  off += 256;
  int* elist   = (int*)(ws + off);  off += (size_t)NE * NP * 4;
  float* pair_w = (float*)(ws + off); off += (size_t)NP * 4;
  bf16* xb   = (bf16*)(ws + off);   off += (size_t)NT * HD * 2;
  bf16* w1t  = (bf16*)(ws + off);   off += (size_t)NE * HD * ID * 2;
  bf16* w2t  = (bf16*)(ws + off);   off += (size_t)NE * HD * ID * 2;
  bf16* hbuf = (bf16*)(ws + off);   off += (size_t)NP * ID * 2;
  bf16* pout = (bf16*)(ws + off);   off += (size_t)KS * NP * HD * 2;

  hipMemsetAsync(counts, 0, 256, stream);
  gate_kernel<<<NT, 64, 0, stream>>>(x, wg, bg, gate_out, xb, pair_w, elist, counts);
  transpose_cvt_kernel<<<dim3(ID / 32, HD / 32, NE), 256, 0, stream>>>(w1, w1t, HD, ID);
  transpose_cvt_kernel<<<dim3(HD / 32, ID / 32, NE), 256, 0, stream>>>(w2, w2t, ID, HD);
  // grid.x = n-tiles (fast; consecutive blocks share the gathered A-tile -> L2 locality)
  // grid.y = m-tile-linear: max sum_e ceil(cnt_e/128) <= 70; 71 with early-exit keeps grid static
  ffn1_kernel<<<dim3(ID / TN, 71), 256, 0, stream>>>(xb, w1t, b1, counts, elist, hbuf);
  ffn2_kernel<<<dim3(HD / TN, 71, KS), 256, 0, stream>>>(hbuf, w2t, b2, counts, elist, pair_w, pout);
  combine_kernel<<<NT, 192, 0, stream>>>(pout, out);
}

// Round 6
// 434.538 us; speedup vs baseline: 1.5436x; 1.5436x over previous
//
#include <hip/hip_runtime.h>
#include <hip/hip_bf16.h>
#include <cmath>

#define NT 4096      // B*S tokens
#define HD 768
#define ID 3072
#define NE 7
#define NP 8192      // NT * TOP_K
#define TM 128
#define TN 128
#define BK 32        // 4 chunks of 8 bf16 per row per iter (per buffer)
#define KS 2         // split-K factor for ffn2

using short8 = __attribute__((ext_vector_type(8))) short;
using f32x4  = __attribute__((ext_vector_type(4))) float;
typedef __hip_bfloat16 bf16;

// async global->LDS, 16B per lane, wave-uniform base + lane*16
typedef const __attribute__((address_space(1))) void* gas_ptr;
typedef __attribute__((address_space(3))) void* las_ptr;
#define GLDS(g, l) __builtin_amdgcn_global_load_lds((gas_ptr)(g), (las_ptr)(l), 16, 0, 0)

__device__ inline float b2f(unsigned short u) {
  unsigned v = (unsigned)u << 16; float f; __builtin_memcpy(&f, &v, 4); return f;
}

// ---------------- gating: logits, top-2 softmax, x->bf16; NO atomics ----------------
__global__ __launch_bounds__(64) void gate_kernel(
    const float* __restrict__ x, const float* __restrict__ wg, const float* __restrict__ bg,
    float* __restrict__ gate_out, bf16* __restrict__ xb,
    float* __restrict__ pair_w, int* __restrict__ tokexp)
{
  int t = blockIdx.x;
  int lane = threadIdx.x;
  const float* xr = x + (size_t)t * HD;
  float acc[NE];
#pragma unroll
  for (int e = 0; e < NE; e++) acc[e] = 0.f;
#pragma unroll
  for (int j = 0; j < HD / 64; j++) {
    int h = lane + j * 64;
    float xv = xr[h];
    xb[(size_t)t * HD + h] = __float2bfloat16(xv);
    const float* wr = wg + (size_t)h * NE;
#pragma unroll
    for (int e = 0; e < NE; e++) acc[e] += xv * wr[e];
  }
#pragma unroll
  for (int e = 0; e < NE; e++) {
    float v = acc[e];
    for (int s = 32; s > 0; s >>= 1) v += __shfl_down(v, s, 64);
    acc[e] = v;
  }
  if (lane == 0) {
    float lg[NE];
#pragma unroll
    for (int e = 0; e < NE; e++) lg[e] = acc[e] + bg[e];
    int i0 = 0;
    for (int e = 1; e < NE; e++) if (lg[e] > lg[i0]) i0 = e;  // first index wins ties
    int i1 = -1;
    for (int e = 0; e < NE; e++) {
      if (e == i0) continue;
      if (i1 < 0 || lg[e] > lg[i1]) i1 = e;
    }
    float v0 = lg[i0], v1 = lg[i1];
    float e1 = expf(v1 - v0);
    float inv = 1.f / (1.f + e1);
    float w0 = inv, w1v = e1 * inv;
    float* go = gate_out + (size_t)t * NE;
#pragma unroll
    for (int e = 0; e < NE; e++) go[e] = 0.f;
    go[i0] = w0; go[i1] = w1v;
    pair_w[2 * t + 0] = w0;
    pair_w[2 * t + 1] = w1v;
    tokexp[2 * t + 0] = i0;
    tokexp[2 * t + 1] = i1;
  }
}

// ---------------- routing: deterministic compaction, one block per expert ----------------
__global__ __launch_bounds__(256) void route_kernel(
    const int* __restrict__ tokexp, int* __restrict__ elist, int* __restrict__ counts)
{
  __shared__ int wcnt[4];
  int e = blockIdx.x;
  int tid = threadIdx.x, wv = tid >> 6, ln = tid & 63;
  int base = 0;
  for (int chunk = 0; chunk < NP; chunk += 256) {
    int p = chunk + tid;
    bool m = (tokexp[p] == e);
    unsigned long long bal = __ballot(m);
    if (ln == 0) wcnt[wv] = __popcll(bal);
    __syncthreads();
    int pre = 0;
#pragma unroll
    for (int w = 0; w < 4; w++) pre += (w < wv) ? wcnt[w] : 0;
    int rank = pre + __popcll(bal & ((1ull << ln) - 1ull));
    if (m) elist[e * NP + base + rank] = p;
    base += wcnt[0] + wcnt[1] + wcnt[2] + wcnt[3];
    __syncthreads();
  }
  if (tid == 0) counts[e] = base;
}

// ---------------- fp32 [E][K][N] -> bf16 [E][N][K] transpose ----------------
__global__ __launch_bounds__(256) void transpose_cvt_kernel(
    const float* __restrict__ src, bf16* __restrict__ dst, int K, int N)
{
  __shared__ float tile[32][33];
  int e = blockIdx.z;
  int n0 = blockIdx.x * 32;
  int k0 = blockIdx.y * 32;
  const float* s = src + (size_t)e * K * N;
  bf16* d = dst + (size_t)e * K * N;
  int tx = threadIdx.x & 31;
  int ty = threadIdx.x >> 5;  // 0..7
#pragma unroll
  for (int i = 0; i < 4; i++)
    tile[ty + i * 8][tx] = s[(size_t)(k0 + ty + i * 8) * N + n0 + tx];
  __syncthreads();
#pragma unroll
  for (int i = 0; i < 4; i++)
    d[(size_t)(n0 + ty + i * 8) * K + k0 + tx] = __float2bfloat16(tile[tx][ty + i * 8]);
}

// ================= shared GEMM machinery =================
// LDS tile (per buffer): [row][physchunk 0..3][8 bf16]; phys slot p holds logical chunk
// kc = p ^ ((row>>1)&3).  Fragment read: phys p = quad ^ ((lr>>1)&3) -> conflict-free
// (measured 0 in R5). Staging: chunk c; row=c>>2, p=c&3 -> lane-contiguous LDS dest
// (GLDS-legal), 4 consecutive lanes cover one row's 64B (permuted within the segment).
// Double-buffered: prefetch tile k+1 while MFMAs consume tile k; ONE barrier/iter.

// ---------------- grouped GEMM 1: h = gelu(x_g @ W1e + b1e), bf16 out ----------------
__global__ __launch_bounds__(256) void ffn1_kernel(
    const bf16* __restrict__ xb, const bf16* __restrict__ w1t, const float* __restrict__ b1,
    const int* __restrict__ counts, const int* __restrict__ elist, bf16* __restrict__ hbuf)
{
  __shared__ bf16 As[2][TM][4][8];   // 2 x 8 KB
  __shared__ bf16 Bs[2][TN][4][8];   // 2 x 8 KB
  __shared__ int plist[TM];

  int tid = threadIdx.x;
  // grid: x = n-tile (fast, shares A across consecutive blocks), y = m-tile-linear
  int e, base = 0, cnt = 0, acct = 0;
  bool found = false;
  for (e = 0; e < NE; e++) {
    cnt = counts[e];
    int tiles = (cnt + TM - 1) / TM;
    if ((int)blockIdx.y < acct + tiles) { base = ((int)blockIdx.y - acct) * TM; found = true; break; }
    acct += tiles;
  }
  if (!found) return;

  if (tid < TM) {
    int r = base + tid;
    plist[tid] = (r < cnt) ? elist[e * NP + r] : -1;
  }
  __syncthreads();

  const int n0 = blockIdx.x * TN;
  const bf16* Bsrc = w1t + (size_t)e * ID * HD;  // [ID][HD] bf16, K-contiguous

  // staging pointers: 2 chunks each for A and B per thread
  const bf16* ag[2]; const bf16* bg2[2];
  bf16* asd[2][2]; bf16* bsd[2][2];
#pragma unroll
  for (int i = 0; i < 2; i++) {
    int c = tid + 256 * i;
    int row = c >> 2, p = c & 3;
    int kc = p ^ ((row >> 1) & 3);           // logical chunk fetched into phys slot p
    int pr = plist[row];
    ag[i]  = xb + (size_t)((pr >= 0 ? pr : 0) >> 1) * HD + kc * 8;
    bg2[i] = Bsrc + (size_t)(n0 + row) * HD + kc * 8;
#pragma unroll
    for (int d = 0; d < 2; d++) {
      asd[d][i] = (bf16*)As + (size_t)d * TM * 32 + (size_t)c * 8;
      bsd[d][i] = (bf16*)Bs + (size_t)d * TN * 32 + (size_t)c * 8;
    }
  }

  int wave = tid >> 6, lane = tid & 63;
  int wm = (wave & 1) << 6, wn = (wave >> 1) << 6;
  int lr = lane & 15, quad = lane >> 4;
  int ph = quad ^ ((lr >> 1) & 3);

  f32x4 acc[4][4] = {};

  const int NIT = HD / BK;  // 24
#pragma unroll
  for (int i = 0; i < 2; i++) { GLDS(ag[i], asd[0][i]); GLDS(bg2[i], bsd[0][i]); }
  __syncthreads();

  for (int it = 0; it < NIT; ++it) {
    int cur = it & 1;
    if (it + 1 < NIT) {
      int koff = (it + 1) * BK;
#pragma unroll
      for (int i = 0; i < 2; i++) {
        GLDS(ag[i] + koff, asd[cur ^ 1][i]);
        GLDS(bg2[i] + koff, bsd[cur ^ 1][i]);
      }
    }
    short8 af[4], bfr[4];
#pragma unroll
    for (int i = 0; i < 4; i++) af[i] = *(const short8*)&As[cur][wm + i * 16 + lr][ph][0];
#pragma unroll
    for (int j = 0; j < 4; j++) bfr[j] = *(const short8*)&Bs[cur][wn + j * 16 + lr][ph][0];
#pragma unroll
    for (int i = 0; i < 4; i++)
#pragma unroll
      for (int j = 0; j < 4; j++)
        acc[i][j] = __builtin_amdgcn_mfma_f32_16x16x32_bf16(af[i], bfr[j], acc[i][j], 0, 0, 0);
    __syncthreads();
  }

  const float* b1e = b1 + (size_t)e * ID;
#pragma unroll
  for (int j = 0; j < 4; j++) {
    int col = n0 + wn + j * 16 + lr;
    float bias = b1e[col];
#pragma unroll
    for (int i = 0; i < 4; i++) {
#pragma unroll
      for (int r = 0; r < 4; r++) {
        int mrow = wm + i * 16 + quad * 4 + r;
        int p = plist[mrow];
        if (p >= 0) {
          float v = acc[i][j][r] + bias;
          float g = 0.5f * v * (1.0f + erff(v * 0.70710678118654752f));  // exact-erf gelu
          hbuf[(size_t)p * ID + col] = __float2bfloat16(g);
        }
      }
    }
  }
}

// ---------------- grouped GEMM 2 (split-K): pout[seg] = (h @ W2e[kseg] [+b2e]) * gate_w ----------------
__global__ __launch_bounds__(256) void ffn2_kernel(
    const bf16* __restrict__ hbuf, const bf16* __restrict__ w2t, const float* __restrict__ b2,
    const int* __restrict__ counts, const int* __restrict__ elist,
    const float* __restrict__ pair_w, bf16* __restrict__ pout)
{
  __shared__ bf16 As[2][TM][4][8];
  __shared__ bf16 Bs[2][TN][4][8];
  __shared__ int plist[TM];

  int tid = threadIdx.x;
  // grid: x = n-tile (fast), y = m-tile-linear, z = k-segment
  int e, base = 0, cnt = 0, acct = 0;
  bool found = false;
  for (e = 0; e < NE; e++) {
    cnt = counts[e];
    int tiles = (cnt + TM - 1) / TM;
    if ((int)blockIdx.y < acct + tiles) { base = ((int)blockIdx.y - acct) * TM; found = true; break; }
    acct += tiles;
  }
  if (!found) return;

  if (tid < TM) {
    int r = base + tid;
    plist[tid] = (r < cnt) ? elist[e * NP + r] : -1;
  }
  __syncthreads();

  const int n0 = blockIdx.x * TN;
  const int seg = blockIdx.z;
  const int kbase = seg * (ID / KS);
  const bf16* Bsrc = w2t + (size_t)e * HD * ID;  // [HD][ID] bf16, K-contiguous

  const bf16* ag[2]; const bf16* bg2[2];
  bf16* asd[2][2]; bf16* bsd[2][2];
#pragma unroll
  for (int i = 0; i < 2; i++) {
    int c = tid + 256 * i;
    int row = c >> 2, p = c & 3;
    int kc = p ^ ((row >> 1) & 3);
    int pr = plist[row];
    ag[i]  = hbuf + (size_t)(pr >= 0 ? pr : 0) * ID + kbase + kc * 8;
    bg2[i] = Bsrc + (size_t)(n0 + row) * ID + kbase + kc * 8;
#pragma unroll
    for (int d = 0; d < 2; d++) {
      asd[d][i] = (bf16*)As + (size_t)d * TM * 32 + (size_t)c * 8;
      bsd[d][i] = (bf16*)Bs + (size_t)d * TN * 32 + (size_t)c * 8;
    }
  }

  int wave = tid >> 6, lane = tid & 63;
  int wm = (wave & 1) << 6, wn = (wave >> 1) << 6;
  int lr = lane & 15, quad = lane >> 4;
  int ph = quad ^ ((lr >> 1) & 3);

  f32x4 acc[4][4] = {};

  const int NIT = (ID / KS) / BK;  // 48
#pragma unroll
  for (int i = 0; i < 2; i++) { GLDS(ag[i], asd[0][i]); GLDS(bg2[i], bsd[0][i]); }
  __syncthreads();

  for (int it = 0; it < NIT; ++it) {
    int cur = it & 1;
    if (it + 1 < NIT) {
      int koff = (it + 1) * BK;
#pragma unroll
      for (int i = 0; i < 2; i++) {
        GLDS(ag[i] + koff, asd[cur ^ 1][i]);
        GLDS(bg2[i] + koff, bsd[cur ^ 1][i]);
      }
    }
    short8 af[4], bfr[4];
#pragma unroll
    for (int i = 0; i < 4; i++) af[i] = *(const short8*)&As[cur][wm + i * 16 + lr][ph][0];
#pragma unroll
    for (int j = 0; j < 4; j++) bfr[j] = *(const short8*)&Bs[cur][wn + j * 16 + lr][ph][0];
#pragma unroll
    for (int i = 0; i < 4; i++)
#pragma unroll
      for (int j = 0; j < 4; j++)
        acc[i][j] = __builtin_amdgcn_mfma_f32_16x16x32_bf16(af[i], bfr[j], acc[i][j], 0, 0, 0);
    __syncthreads();
  }

  const float* b2e = b2 + (size_t)e * HD;
#pragma unroll
  for (int j = 0; j < 4; j++) {
    int col = n0 + wn + j * 16 + lr;
    float bias = (seg == 0) ? b2e[col] : 0.f;
#pragma unroll
    for (int i = 0; i < 4; i++) {
#pragma unroll
      for (int r = 0; r < 4; r++) {
        int mrow = wm + i * 16 + quad * 4 + r;
        int p = plist[mrow];
        if (p >= 0) {
          float v = (acc[i][j][r] + bias) * pair_w[p];
          pout[((size_t)seg * NP + p) * HD + col] = __float2bfloat16(v);
        }
      }
    }
  }
}

// ---------------- combine: out[t] = sum over 2 experts x KS k-segments ----------------
__global__ __launch_bounds__(192) void combine_kernel(
    const bf16* __restrict__ pout, float* __restrict__ out)
{
  int t = blockIdx.x, j = threadIdx.x;  // 192 threads = 768/4
  f32x4 o = {0.f, 0.f, 0.f, 0.f};
#pragma unroll
  for (int s = 0; s < KS; s++) {
#pragma unroll
    for (int k = 0; k < 2; k++) {
      const ushort4* v = (const ushort4*)(pout + ((size_t)s * NP + 2 * t + k) * HD);
      ushort4 u = v[j];
      o[0] += b2f(u.x); o[1] += b2f(u.y); o[2] += b2f(u.z); o[3] += b2f(u.w);
    }
  }
  ((f32x4*)(out + (size_t)t * HD))[j] = o;
}

extern "C" void kernel_launch(void* const* d_in, const int* in_sizes, int n_in,
                              void* d_out, int out_size, void* d_ws, size_t ws_size,
                              hipStream_t stream)
{
  const float* x  = (const float*)d_in[0];
  const float* wg = (const float*)d_in[1];
  const float* bg = (const float*)d_in[2];
  const float* w1 = (const float*)d_in[3];
  const float* b1 = (const float*)d_in[4];
  const float* w2 = (const float*)d_in[5];
  const float* b2 = (const float*)d_in[6];
  float* out = (float*)d_out;
  float* gate_out = out + (size_t)NT * HD;  // second output [B,S,E]

  // workspace layout (~141 MB total, all 16B-aligned offsets)
  char* ws = (char*)d_ws;
  size_t off = 0;
  int* counts  = (int*)(ws + off);  off += 256;
  int* tokexp  = (int*)(ws + off);  off += (size_t)NP * 4;
  int* elist   = (int*)(ws + off);  off += (size_t)NE * NP * 4;
  float* pair_w = (float*)(ws + off); off += (size_t)NP * 4;
  bf16* xb   = (bf16*)(ws + off);   off += (size_t)NT * HD * 2;
  bf16* w1t  = (bf16*)(ws + off);   off += (size_t)NE * HD * ID * 2;
  bf16* w2t  = (bf16*)(ws + off);   off += (size_t)NE * HD * ID * 2;
  bf16* hbuf = (bf16*)(ws + off);   off += (size_t)NP * ID * 2;
  bf16* pout = (bf16*)(ws + off);   off += (size_t)KS * NP * HD * 2;

  gate_kernel<<<NT, 64, 0, stream>>>(x, wg, bg, gate_out, xb, pair_w, tokexp);
  route_kernel<<<NE, 256, 0, stream>>>(tokexp, elist, counts);
  transpose_cvt_kernel<<<dim3(ID / 32, HD / 32, NE), 256, 0, stream>>>(w1, w1t, HD, ID);
  transpose_cvt_kernel<<<dim3(HD / 32, ID / 32, NE), 256, 0, stream>>>(w2, w2t, ID, HD);
  // grid.x = n-tiles (fast; consecutive blocks share the gathered A-tile -> L2 locality)
  // grid.y = m-tile-linear: max sum_e ceil(cnt_e/128) <= 70; 71 with early-exit keeps grid static
  ffn1_kernel<<<dim3(ID / TN, 71), 256, 0, stream>>>(xb, w1t, b1, counts, elist, hbuf);
  ffn2_kernel<<<dim3(HD / TN, 71, KS), 256, 0, stream>>>(hbuf, w2t, b2, counts, elist, pair_w, pout);
  combine_kernel<<<NT, 192, 0, stream>>>(pout, out);
}

// Round 7
// 412.059 us; speedup vs baseline: 1.6278x; 1.0546x over previous
//
#include <hip/hip_runtime.h>
#include <hip/hip_bf16.h>
#include <cmath>

#define NT 4096      // B*S tokens
#define HD 768
#define ID 3072
#define NE 7
#define NP 8192      // NT * TOP_K
#define TM 128
#define TN 128
#define BK 32        // 4 chunks of 8 bf16 per row per iter (per buffer)
#define KS 2         // split-K factor for ffn2
#define NT2 (HD / TN)   // 6 n-tiles in ffn2
#define SLOTS 384    // worst-case tiles per XCD in ffn2 (32 mtiles * 6 n * 2 pairs)

using short8 = __attribute__((ext_vector_type(8))) short;
using f32x4  = __attribute__((ext_vector_type(4))) float;
typedef __hip_bfloat16 bf16;

// async global->LDS, 16B per lane, wave-uniform base + lane*16
typedef const __attribute__((address_space(1))) void* gas_ptr;
typedef __attribute__((address_space(3))) void* las_ptr;
#define GLDS(g, l) __builtin_amdgcn_global_load_lds((gas_ptr)(g), (las_ptr)(l), 16, 0, 0)

__device__ inline float b2f(unsigned short u) {
  unsigned v = (unsigned)u << 16; float f; __builtin_memcpy(&f, &v, 4); return f;
}

// ---------------- gating: logits, top-2 softmax, x->bf16; NO atomics ----------------
__global__ __launch_bounds__(64) void gate_kernel(
    const float* __restrict__ x, const float* __restrict__ wg, const float* __restrict__ bg,
    float* __restrict__ gate_out, bf16* __restrict__ xb,
    float* __restrict__ pair_w, int* __restrict__ tokexp)
{
  int t = blockIdx.x;
  int lane = threadIdx.x;
  const float* xr = x + (size_t)t * HD;
  float acc[NE];
#pragma unroll
  for (int e = 0; e < NE; e++) acc[e] = 0.f;
#pragma unroll
  for (int j = 0; j < HD / 64; j++) {
    int h = lane + j * 64;
    float xv = xr[h];
    xb[(size_t)t * HD + h] = __float2bfloat16(xv);
    const float* wr = wg + (size_t)h * NE;
#pragma unroll
    for (int e = 0; e < NE; e++) acc[e] += xv * wr[e];
  }
#pragma unroll
  for (int e = 0; e < NE; e++) {
    float v = acc[e];
    for (int s = 32; s > 0; s >>= 1) v += __shfl_down(v, s, 64);
    acc[e] = v;
  }
  if (lane == 0) {
    float lg[NE];
#pragma unroll
    for (int e = 0; e < NE; e++) lg[e] = acc[e] + bg[e];
    int i0 = 0;
    for (int e = 1; e < NE; e++) if (lg[e] > lg[i0]) i0 = e;  // first index wins ties
    int i1 = -1;
    for (int e = 0; e < NE; e++) {
      if (e == i0) continue;
      if (i1 < 0 || lg[e] > lg[i1]) i1 = e;
    }
    float v0 = lg[i0], v1 = lg[i1];
    float e1 = expf(v1 - v0);
    float inv = 1.f / (1.f + e1);
    float w0 = inv, w1v = e1 * inv;
    float* go = gate_out + (size_t)t * NE;
#pragma unroll
    for (int e = 0; e < NE; e++) go[e] = 0.f;
    go[i0] = w0; go[i1] = w1v;
    pair_w[2 * t + 0] = w0;
    pair_w[2 * t + 1] = w1v;
    tokexp[2 * t + 0] = i0;
    tokexp[2 * t + 1] = i1;
  }
}

// ---------------- routing: deterministic compaction, one block per expert ----------------
__global__ __launch_bounds__(256) void route_kernel(
    const int* __restrict__ tokexp, int* __restrict__ elist, int* __restrict__ counts)
{
  __shared__ int wcnt[4];
  int e = blockIdx.x;
  int tid = threadIdx.x, wv = tid >> 6, ln = tid & 63;
  int base = 0;
  for (int chunk = 0; chunk < NP; chunk += 256) {
    int p = chunk + tid;
    bool m = (tokexp[p] == e);
    unsigned long long bal = __ballot(m);
    if (ln == 0) wcnt[wv] = __popcll(bal);
    __syncthreads();
    int pre = 0;
#pragma unroll
    for (int w = 0; w < 4; w++) pre += (w < wv) ? wcnt[w] : 0;
    int rank = pre + __popcll(bal & ((1ull << ln) - 1ull));
    if (m) elist[e * NP + base + rank] = p;
    base += wcnt[0] + wcnt[1] + wcnt[2] + wcnt[3];
    __syncthreads();
  }
  if (tid == 0) counts[e] = base;
}

// ---------------- fp32 [E][K][N] -> bf16 [E][N][K] transpose, 64x64 tiles ----------------
// Phase1: float4 coalesced reads -> LDS [64][65] (pad 65 -> conflict-free scalar writes).
// Phase2: 16 lanes assemble one 128B contiguous bf16 row-segment -> ushort4 stores.
__global__ __launch_bounds__(256) void transpose_cvt_kernel(
    const float* __restrict__ src, bf16* __restrict__ dst, int K, int N)
{
  __shared__ float tile[64][65];
  int e = blockIdx.z;
  int n0 = blockIdx.x * 64;
  int k0 = blockIdx.y * 64;
  const float* s = src + (size_t)e * K * N;
  bf16* d = dst + (size_t)e * K * N;
  int t = threadIdx.x;
  {
    int kk = t >> 4;            // 0..15
    int nc = (t & 15) << 2;     // 0,4,...,60
#pragma unroll
    for (int r = 0; r < 4; r++) {
      int k = kk + r * 16;
      float4 v = *(const float4*)(s + (size_t)(k0 + k) * N + n0 + nc);
      tile[k][nc + 0] = v.x; tile[k][nc + 1] = v.y;
      tile[k][nc + 2] = v.z; tile[k][nc + 3] = v.w;
    }
  }
  __syncthreads();
  {
    int c = t & 15;             // k-chunk (4 elems)
    int nbase = t >> 4;         // 0..15
#pragma unroll
    for (int r = 0; r < 4; r++) {
      int n = nbase + r * 16;
      bf16 tmp[4];
#pragma unroll
      for (int i = 0; i < 4; i++) tmp[i] = __float2bfloat16(tile[4 * c + i][n]);
      ushort4 u; __builtin_memcpy(&u, tmp, 8);
      *(ushort4*)(d + (size_t)(n0 + n) * K + k0 + 4 * c) = u;
    }
  }
}

// ================= shared GEMM machinery =================
// LDS tile (per buffer): [row][physchunk 0..3][8 bf16]; phys slot p holds logical chunk
// kc = p ^ ((row>>1)&3).  Fragment read: phys p = quad ^ ((lr>>1)&3) -> conflict-free
// (measured 0 in R5/R6). Staging: chunk c; row=c>>2, p=c&3 -> lane-contiguous LDS dest
// (GLDS-legal), 4 consecutive lanes cover one row's 64B (permuted within the segment).
// Double-buffered: prefetch tile k+1 while MFMAs consume tile k; ONE barrier/iter.

// ---------------- grouped GEMM 1: h = gelu(x_g @ W1e + b1e), bf16 out ----------------
__global__ __launch_bounds__(256) void ffn1_kernel(
    const bf16* __restrict__ xb, const bf16* __restrict__ w1t, const float* __restrict__ b1,
    const int* __restrict__ counts, const int* __restrict__ elist, bf16* __restrict__ hbuf)
{
  __shared__ bf16 As[2][TM][4][8];   // 2 x 8 KB
  __shared__ bf16 Bs[2][TN][4][8];   // 2 x 8 KB
  __shared__ int plist[TM];

  int tid = threadIdx.x;
  // grid: x = n-tile (fast, shares A across consecutive blocks), y = m-tile-linear
  int e, base = 0, cnt = 0, acct = 0;
  bool found = false;
  for (e = 0; e < NE; e++) {
    cnt = counts[e];
    int tiles = (cnt + TM - 1) / TM;
    if ((int)blockIdx.y < acct + tiles) { base = ((int)blockIdx.y - acct) * TM; found = true; break; }
    acct += tiles;
  }
  if (!found) return;

  if (tid < TM) {
    int r = base + tid;
    plist[tid] = (r < cnt) ? elist[e * NP + r] : -1;
  }
  __syncthreads();

  const int n0 = blockIdx.x * TN;
  const bf16* Bsrc = w1t + (size_t)e * ID * HD;  // [ID][HD] bf16, K-contiguous

  const bf16* ag[2]; const bf16* bg2[2];
  bf16* asd[2][2]; bf16* bsd[2][2];
#pragma unroll
  for (int i = 0; i < 2; i++) {
    int c = tid + 256 * i;
    int row = c >> 2, p = c & 3;
    int kc = p ^ ((row >> 1) & 3);           // logical chunk fetched into phys slot p
    int pr = plist[row];
    ag[i]  = xb + (size_t)((pr >= 0 ? pr : 0) >> 1) * HD + kc * 8;
    bg2[i] = Bsrc + (size_t)(n0 + row) * HD + kc * 8;
#pragma unroll
    for (int d = 0; d < 2; d++) {
      asd[d][i] = (bf16*)As + (size_t)d * TM * 32 + (size_t)c * 8;
      bsd[d][i] = (bf16*)Bs + (size_t)d * TN * 32 + (size_t)c * 8;
    }
  }

  int wave = tid >> 6, lane = tid & 63;
  int wm = (wave & 1) << 6, wn = (wave >> 1) << 6;
  int lr = lane & 15, quad = lane >> 4;
  int ph = quad ^ ((lr >> 1) & 3);

  f32x4 acc[4][4] = {};

  const int NIT = HD / BK;  // 24
#pragma unroll
  for (int i = 0; i < 2; i++) { GLDS(ag[i], asd[0][i]); GLDS(bg2[i], bsd[0][i]); }
  __syncthreads();

  for (int it = 0; it < NIT; ++it) {
    int cur = it & 1;
    if (it + 1 < NIT) {
      int koff = (it + 1) * BK;
#pragma unroll
      for (int i = 0; i < 2; i++) {
        GLDS(ag[i] + koff, asd[cur ^ 1][i]);
        GLDS(bg2[i] + koff, bsd[cur ^ 1][i]);
      }
    }
    short8 af[4], bfr[4];
#pragma unroll
    for (int i = 0; i < 4; i++) af[i] = *(const short8*)&As[cur][wm + i * 16 + lr][ph][0];
#pragma unroll
    for (int j = 0; j < 4; j++) bfr[j] = *(const short8*)&Bs[cur][wn + j * 16 + lr][ph][0];
#pragma unroll
    for (int i = 0; i < 4; i++)
#pragma unroll
      for (int j = 0; j < 4; j++)
        acc[i][j] = __builtin_amdgcn_mfma_f32_16x16x32_bf16(af[i], bfr[j], acc[i][j], 0, 0, 0);
    __syncthreads();
  }

  const float* b1e = b1 + (size_t)e * ID;
#pragma unroll
  for (int j = 0; j < 4; j++) {
    int col = n0 + wn + j * 16 + lr;
    float bias = b1e[col];
#pragma unroll
    for (int i = 0; i < 4; i++) {
#pragma unroll
      for (int r = 0; r < 4; r++) {
        int mrow = wm + i * 16 + quad * 4 + r;
        int p = plist[mrow];
        if (p >= 0) {
          float v = acc[i][j][r] + bias;
          float g = 0.5f * v * (1.0f + erff(v * 0.70710678118654752f));  // exact-erf gelu
          hbuf[(size_t)p * ID + col] = __float2bfloat16(g);
        }
      }
    }
  }
}

// ---------------- grouped GEMM 2 (split-K, XCD-pinned): pout[seg] = (h @ W2e[kseg] [+b2e]) * gate_w
// grid = (8, SLOTS): blockIdx.x == linear%8 == XCD (round-robin). Pair p=2e+seg pinned to
// XCD p%8 so its B-panel (2.36 MB) stays L2-resident and each gathered A-tile is fetched
// once per XCD (n varies fastest within a pair).
__global__ __launch_bounds__(256) void ffn2_kernel(
    const bf16* __restrict__ hbuf, const bf16* __restrict__ w2t, const float* __restrict__ b2,
    const int* __restrict__ counts, const int* __restrict__ elist,
    const float* __restrict__ pair_w, bf16* __restrict__ pout)
{
  __shared__ bf16 As[2][TM][4][8];
  __shared__ bf16 Bs[2][TN][4][8];
  __shared__ int plist[TM];

  int tid = threadIdx.x;
  int xcd = blockIdx.x;
  int slot = blockIdx.y;
  int e = 0, seg = 0, base = 0, cnt = 0, n0 = 0;
  bool found = false;
  for (int p = xcd; p < 2 * NE; p += 8) {
    int pe = p >> 1;
    int c = counts[pe];
    int tiles = ((c + TM - 1) / TM) * NT2;
    if (slot < tiles) {
      e = pe; seg = p & 1; cnt = c;
      base = (slot / NT2) * TM;
      n0 = (slot % NT2) * TN;
      found = true; break;
    }
    slot -= tiles;
  }
  if (!found) return;

  if (tid < TM) {
    int r = base + tid;
    plist[tid] = (r < cnt) ? elist[e * NP + r] : -1;
  }
  __syncthreads();

  const int kbase = seg * (ID / KS);
  const bf16* Bsrc = w2t + (size_t)e * HD * ID;  // [HD][ID] bf16, K-contiguous

  const bf16* ag[2]; const bf16* bg2[2];
  bf16* asd[2][2]; bf16* bsd[2][2];
#pragma unroll
  for (int i = 0; i < 2; i++) {
    int c = tid + 256 * i;
    int row = c >> 2, p = c & 3;
    int kc = p ^ ((row >> 1) & 3);
    int pr = plist[row];
    ag[i]  = hbuf + (size_t)(pr >= 0 ? pr : 0) * ID + kbase + kc * 8;
    bg2[i] = Bsrc + (size_t)(n0 + row) * ID + kbase + kc * 8;
#pragma unroll
    for (int d = 0; d < 2; d++) {
      asd[d][i] = (bf16*)As + (size_t)d * TM * 32 + (size_t)c * 8;
      bsd[d][i] = (bf16*)Bs + (size_t)d * TN * 32 + (size_t)c * 8;
    }
  }

  int wave = tid >> 6, lane = tid & 63;
  int wm = (wave & 1) << 6, wn = (wave >> 1) << 6;
  int lr = lane & 15, quad = lane >> 4;
  int ph = quad ^ ((lr >> 1) & 3);

  f32x4 acc[4][4] = {};

  const int NIT = (ID / KS) / BK;  // 48
#pragma unroll
  for (int i = 0; i < 2; i++) { GLDS(ag[i], asd[0][i]); GLDS(bg2[i], bsd[0][i]); }
  __syncthreads();

  for (int it = 0; it < NIT; ++it) {
    int cur = it & 1;
    if (it + 1 < NIT) {
      int koff = (it + 1) * BK;
#pragma unroll
      for (int i = 0; i < 2; i++) {
        GLDS(ag[i] + koff, asd[cur ^ 1][i]);
        GLDS(bg2[i] + koff, bsd[cur ^ 1][i]);
      }
    }
    short8 af[4], bfr[4];
#pragma unroll
    for (int i = 0; i < 4; i++) af[i] = *(const short8*)&As[cur][wm + i * 16 + lr][ph][0];
#pragma unroll
    for (int j = 0; j < 4; j++) bfr[j] = *(const short8*)&Bs[cur][wn + j * 16 + lr][ph][0];
#pragma unroll
    for (int i = 0; i < 4; i++)
#pragma unroll
      for (int j = 0; j < 4; j++)
        acc[i][j] = __builtin_amdgcn_mfma_f32_16x16x32_bf16(af[i], bfr[j], acc[i][j], 0, 0, 0);
    __syncthreads();
  }

  const float* b2e = b2 + (size_t)e * HD;
#pragma unroll
  for (int j = 0; j < 4; j++) {
    int col = n0 + wn + j * 16 + lr;
    float bias = (seg == 0) ? b2e[col] : 0.f;
#pragma unroll
    for (int i = 0; i < 4; i++) {
#pragma unroll
      for (int r = 0; r < 4; r++) {
        int mrow = wm + i * 16 + quad * 4 + r;
        int p = plist[mrow];
        if (p >= 0) {
          float v = (acc[i][j][r] + bias) * pair_w[p];
          pout[((size_t)seg * NP + p) * HD + col] = __float2bfloat16(v);
        }
      }
    }
  }
}

// ---------------- combine: out[t] = sum over 2 experts x KS k-segments ----------------
__global__ __launch_bounds__(192) void combine_kernel(
    const bf16* __restrict__ pout, float* __restrict__ out)
{
  int t = blockIdx.x, j = threadIdx.x;  // 192 threads = 768/4
  f32x4 o = {0.f, 0.f, 0.f, 0.f};
#pragma unroll
  for (int s = 0; s < KS; s++) {
#pragma unroll
    for (int k = 0; k < 2; k++) {
      const ushort4* v = (const ushort4*)(pout + ((size_t)s * NP + 2 * t + k) * HD);
      ushort4 u = v[j];
      o[0] += b2f(u.x); o[1] += b2f(u.y); o[2] += b2f(u.z); o[3] += b2f(u.w);
    }
  }
  ((f32x4*)(out + (size_t)t * HD))[j] = o;
}

extern "C" void kernel_launch(void* const* d_in, const int* in_sizes, int n_in,
                              void* d_out, int out_size, void* d_ws, size_t ws_size,
                              hipStream_t stream)
{
  const float* x  = (const float*)d_in[0];
  const float* wg = (const float*)d_in[1];
  const float* bg = (const float*)d_in[2];
  const float* w1 = (const float*)d_in[3];
  const float* b1 = (const float*)d_in[4];
  const float* w2 = (const float*)d_in[5];
  const float* b2 = (const float*)d_in[6];
  float* out = (float*)d_out;
  float* gate_out = out + (size_t)NT * HD;  // second output [B,S,E]

  // workspace layout (~141 MB total, all 16B-aligned offsets)
  char* ws = (char*)d_ws;
  size_t off = 0;
  int* counts  = (int*)(ws + off);  off += 256;
  int* tokexp  = (int*)(ws + off);  off += (size_t)NP * 4;
  int* elist   = (int*)(ws + off);  off += (size_t)NE * NP * 4;
  float* pair_w = (float*)(ws + off); off += (size_t)NP * 4;
  bf16* xb   = (bf16*)(ws + off);   off += (size_t)NT * HD * 2;
  bf16* w1t  = (bf16*)(ws + off);   off += (size_t)NE * HD * ID * 2;
  bf16* w2t  = (bf16*)(ws + off);   off += (size_t)NE * HD * ID * 2;
  bf16* hbuf = (bf16*)(ws + off);   off += (size_t)NP * ID * 2;
  bf16* pout = (bf16*)(ws + off);   off += (size_t)KS * NP * HD * 2;

  gate_kernel<<<NT, 64, 0, stream>>>(x, wg, bg, gate_out, xb, pair_w, tokexp);
  route_kernel<<<NE, 256, 0, stream>>>(tokexp, elist, counts);
  transpose_cvt_kernel<<<dim3(ID / 64, HD / 64, NE), 256, 0, stream>>>(w1, w1t, HD, ID);
  transpose_cvt_kernel<<<dim3(HD / 64, ID / 64, NE), 256, 0, stream>>>(w2, w2t, ID, HD);
  // ffn1: grid.x = n-tiles (fast; consecutive blocks share the gathered A-tile)
  ffn1_kernel<<<dim3(ID / TN, 71), 256, 0, stream>>>(xb, w1t, b1, counts, elist, hbuf);
  // ffn2: XCD-pinned (grid.x = 8 = XCD id under %8 round-robin)
  ffn2_kernel<<<dim3(8, SLOTS), 256, 0, stream>>>(hbuf, w2t, b2, counts, elist, pair_w, pout);
  combine_kernel<<<NT, 192, 0, stream>>>(pout, out);
}